// Round 3
// baseline (343.353 us; speedup 1.0000x reference)
//
#include <hip/hip_runtime.h>

#define NSEQ   8
#define HEADS  16
#define HSIZE  128          // head_size = 2048/16
#define HIDDEN 2048
#define BT     128          // output tile edge
#define LDS_PAD 8
#define LDS_ROW (HSIZE + LDS_PAD)   // 136 bf16 elems = 272 B row stride (16B-aligned, 2-way bank alias = free)

typedef __attribute__((ext_vector_type(8))) short  bf16x8;
typedef __attribute__((ext_vector_type(4))) float  f32x4;

struct SeqMap {
    int       s[NSEQ];
    int       row_off[NSEQ];     // input row offset (prefix sum of s)
    long long out_off[NSEQ];     // output element offset (16 * prefix sum of s^2)
    int       t[NSEQ];           // tiles per dim = ceil(s/128)
    int       blk_start[NSEQ];   // first block id of this seq
};

__device__ __forceinline__ unsigned short f2bf(float x) {
    // RNE fp32 -> bf16 (no NaN special-casing needed; inputs are small normals)
    unsigned int u = __builtin_bit_cast(unsigned int, x);
    u += 0x7fffu + ((u >> 16) & 1u);
    return (unsigned short)(u >> 16);
}

__global__ __launch_bounds__(256, 2) void qkt_varlen_kernel(
    const float* __restrict__ A, const float* __restrict__ B,
    float* __restrict__ out, SeqMap map)
{
    __shared__ unsigned short lA[BT * LDS_ROW];
    __shared__ unsigned short lB[BT * LDS_ROW];

    const int bid = blockIdx.x;

    // ---- block -> (seq i, head h, tile_r, tile_c) ----
    int i = 0;
    #pragma unroll
    for (int k = 1; k < NSEQ; ++k) if (bid >= map.blk_start[k]) i = k;
    const int local        = bid - map.blk_start[i];
    const int t            = map.t[i];
    const int tilesPerHead = t * t;
    const int h            = local / tilesPerHead;
    const int rem          = local - h * tilesPerHead;
    const int tr           = rem / t;
    const int tc           = rem - tr * t;
    const int s            = map.s[i];
    const int row0         = map.row_off[i];

    const int tid = threadIdx.x;

    // ---- stage A rows [tr*128,+128) and B rows [tc*128,+128), head h, K=128 ----
    // 256 threads x float4: 32 float4/row -> 8 rows/iter -> 16 iters per matrix.
    #pragma unroll
    for (int it = 0; it < 16; ++it) {
        const int lin = it * 256 + tid;
        const int r   = lin >> 5;        // 0..127
        const int c4  = lin & 31;        // float4 index within the 128-wide K
        const size_t colbase = (size_t)h * HSIZE + (size_t)c4 * 4;

        // A panel
        {
            const int gr = tr * BT + r;
            float4 v = make_float4(0.f, 0.f, 0.f, 0.f);
            if (gr < s)
                v = *(const float4*)(A + (size_t)(row0 + gr) * HIDDEN + colbase);
            ushort4 p;
            p.x = f2bf(v.x); p.y = f2bf(v.y); p.z = f2bf(v.z); p.w = f2bf(v.w);
            *(ushort4*)&lA[r * LDS_ROW + c4 * 4] = p;
        }
        // B panel
        {
            const int gr = tc * BT + r;
            float4 v = make_float4(0.f, 0.f, 0.f, 0.f);
            if (gr < s)
                v = *(const float4*)(B + (size_t)(row0 + gr) * HIDDEN + colbase);
            ushort4 p;
            p.x = f2bf(v.x); p.y = f2bf(v.y); p.z = f2bf(v.z); p.w = f2bf(v.w);
            *(ushort4*)&lB[r * LDS_ROW + c4 * 4] = p;
        }
    }
    __syncthreads();

    // ---- MFMA: 4 waves (2x2), each wave a 64x64 sub-tile of 4x4 16x16 frags ----
    const int lane = tid & 63;
    const int w    = tid >> 6;
    const int wr   = w >> 1;         // 0..1
    const int wc   = w & 1;          // 0..1
    const int lrow = lane & 15;      // fragment row (A) / col (B)
    const int kgrp = lane >> 4;      // 0..3 -> k sub-offset *8

    f32x4 acc[4][4];
    #pragma unroll
    for (int m = 0; m < 4; ++m)
        #pragma unroll
        for (int n = 0; n < 4; ++n)
            acc[m][n] = (f32x4){0.f, 0.f, 0.f, 0.f};

    #pragma unroll
    for (int kk = 0; kk < 4; ++kk) {                 // K = 4 * 32
        const int koff = kk * 32 + kgrp * 8;
        bf16x8 af[4], bfr[4];
        #pragma unroll
        for (int m = 0; m < 4; ++m)
            af[m] = *(const bf16x8*)&lA[(wr * 64 + m * 16 + lrow) * LDS_ROW + koff];
        #pragma unroll
        for (int n = 0; n < 4; ++n)
            bfr[n] = *(const bf16x8*)&lB[(wc * 64 + n * 16 + lrow) * LDS_ROW + koff];
        #pragma unroll
        for (int m = 0; m < 4; ++m)
            #pragma unroll
            for (int n = 0; n < 4; ++n)
                acc[m][n] = __builtin_amdgcn_mfma_f32_16x16x32_bf16(
                                af[m], bfr[n], acc[m][n], 0, 0, 0);
    }

    // ---- epilogue: C/D layout col = lane&15, row = (lane>>4)*4 + reg ----
    const long long obase = map.out_off[i] + (long long)h * s * s;
    #pragma unroll
    for (int m = 0; m < 4; ++m) {
        #pragma unroll
        for (int n = 0; n < 4; ++n) {
            const int c = tc * BT + wc * 64 + n * 16 + lrow;
            if (c >= s) continue;
            const int rb = tr * BT + wr * 64 + m * 16 + kgrp * 4;
            #pragma unroll
            for (int j = 0; j < 4; ++j) {
                const int r = rb + j;
                if (r < s)
                    out[obase + (long long)r * s + c] = acc[m][n][j];
            }
        }
    }
}

extern "C" void kernel_launch(void* const* d_in, const int* in_sizes, int n_in,
                              void* d_out, int out_size, void* d_ws, size_t ws_size,
                              hipStream_t stream) {
    const float* A = (const float*)d_in[0];
    const float* B = (const float*)d_in[1];
    float* out = (float*)d_out;

    // SEQLEN is a module-level constant in the reference; mirror it here and
    // build the mapping host-side (seqlen device values are identical).
    static const int S[NSEQ] = {1024, 768, 512, 1536, 256, 1280, 512, 1024};

    SeqMap map;
    int row = 0, blk = 0;
    long long ooff = 0;
    for (int i = 0; i < NSEQ; ++i) {
        const int t = (S[i] + BT - 1) / BT;
        map.s[i]         = S[i];
        map.row_off[i]   = row;
        map.out_off[i]   = ooff;
        map.t[i]         = t;
        map.blk_start[i] = blk;
        row  += S[i];
        ooff += (long long)HEADS * S[i] * S[i];
        blk  += HEADS * t * t;
    }

    qkt_varlen_kernel<<<blk, 256, 0, stream>>>(A, B, out, map);
}

// Round 4
// 170.149 us; speedup vs baseline: 2.0180x; 2.0180x over previous
//
#include <hip/hip_runtime.h>

#define NSEQ   8
#define HEADS  16
#define HSIZE  128          // head_size = 2048/16
#define HIDDEN 2048
#define BT     128          // tile edge
#define LDS_PAD 8
#define LDS_ROW (HSIZE + LDS_PAD)   // 136 shorts = 272 B stride; 2-way bank alias = free (m136)

typedef __attribute__((ext_vector_type(8))) short  bf16x8;
typedef __attribute__((ext_vector_type(4))) float  f32x4;

struct SeqMap {
    int       s[NSEQ];
    int       row_off[NSEQ];     // input row offset (original concat order)
    long long out_off[NSEQ];     // output element offset (original concat order)
    int       t[NSEQ];           // tiles per dim = s/128 (all seqlens % 128 == 0)
    int       blk_start[NSEQ];   // first block id of this entry (sorted-desc-by-t order)
    int       nblk;
};

__device__ __forceinline__ unsigned short f2bf(float x) {
    // RNE fp32 -> bf16
    unsigned int u = __builtin_bit_cast(unsigned int, x);
    u += 0x7fffu + ((u >> 16) & 1u);
    return (unsigned short)(u >> 16);
}

__global__ __launch_bounds__(256, 2) void qkt_strip_kernel(
    const float* __restrict__ A, const float* __restrict__ B,
    float* __restrict__ out, SeqMap map)
{
    __shared__ unsigned short lds[2][BT * LDS_ROW];   // 69632 B -> 2 blocks/CU

    // bijective XCD chunk swizzle (nblk % 8 == 0): same-(seq,head) strips share an XCD's L2
    const int cpx = map.nblk >> 3;
    const int bid = ((int)blockIdx.x % 8) * cpx + ((int)blockIdx.x / 8);

    // ---- block -> (seq entry i, head h, tile_row tr) ----
    int i = 0;
    #pragma unroll
    for (int k = 1; k < NSEQ; ++k) if (bid >= map.blk_start[k]) i = k;
    const int local = bid - map.blk_start[i];
    const int t     = map.t[i];
    const int h     = local / t;
    const int tr    = local - h * t;
    const int s     = map.s[i];
    const int row0  = map.row_off[i];

    const int tid  = threadIdx.x;
    const int r0   = tid >> 5;           // staging row base (0..7)
    const int c4   = tid & 31;           // staging float4 column
    const size_t hcol = (size_t)h * HSIZE + (size_t)c4 * 4;

    const int lane = tid & 63;
    const int w    = tid >> 6;
    const int wr   = w >> 1;             // wave row half
    const int wc   = w & 1;              // wave col half
    const int lrow = lane & 15;
    const int kgrp = lane >> 4;          // k sub-offset *8

    unsigned short* ldsw0 = &lds[0][r0 * LDS_ROW + c4 * 4];
    unsigned short* ldsw1 = &lds[1][r0 * LDS_ROW + c4 * 4];

    // ---- prologue: A panel -> lds[0], B tile 0 -> lds[1] (32 loads in flight) ----
    {
        const float* sa = A + (size_t)(row0 + tr * BT + r0) * HIDDEN + hcol;
        const float* sb = B + (size_t)(row0 + r0) * HIDDEN + hcol;
        float4 ga[16], gb[16];
        #pragma unroll
        for (int it = 0; it < 16; ++it) ga[it] = *(const float4*)(sa + (size_t)it * 8 * HIDDEN);
        #pragma unroll
        for (int it = 0; it < 16; ++it) gb[it] = *(const float4*)(sb + (size_t)it * 8 * HIDDEN);
        #pragma unroll
        for (int it = 0; it < 16; ++it) {
            ushort4 p; p.x=f2bf(ga[it].x); p.y=f2bf(ga[it].y); p.z=f2bf(ga[it].z); p.w=f2bf(ga[it].w);
            *(ushort4*)(ldsw0 + it * 8 * LDS_ROW) = p;
        }
        #pragma unroll
        for (int it = 0; it < 16; ++it) {
            ushort4 p; p.x=f2bf(gb[it].x); p.y=f2bf(gb[it].y); p.z=f2bf(gb[it].z); p.w=f2bf(gb[it].w);
            *(ushort4*)(ldsw1 + it * 8 * LDS_ROW) = p;
        }
    }
    __syncthreads();

    // ---- A fragments -> registers (persist for the whole strip) ----
    bf16x8 af[4][4];
    #pragma unroll
    for (int m = 0; m < 4; ++m)
        #pragma unroll
        for (int kk = 0; kk < 4; ++kk)
            af[m][kk] = *(const bf16x8*)&lds[0][(wr*64 + m*16 + lrow) * LDS_ROW + kk*32 + kgrp*8];
    __syncthreads();   // all waves' af reads done -> lds[0] reusable as B buffer

    int cur = 1;
    const long long obase = map.out_off[i] + (long long)h * s * s;
    float* orow = out + obase
                + (long long)(tr * BT + wr * 64 + kgrp * 4) * s
                + (wc * 64 + lrow);

    for (int tc = 0; tc < t; ++tc) {
        const bool has_next = (tc + 1 < t);

        // 1) issue next B-tile global loads (consumed after MFMA; latency hides)
        float4 g[16];
        if (has_next) {
            const float* sb = B + (size_t)(row0 + (tc + 1) * BT + r0) * HIDDEN + hcol;
            #pragma unroll
            for (int it = 0; it < 16; ++it) g[it] = *(const float4*)(sb + (size_t)it * 8 * HIDDEN);
        }

        // 2) compute current tile from lds[cur]
        f32x4 acc[4][4];
        #pragma unroll
        for (int m = 0; m < 4; ++m)
            #pragma unroll
            for (int n = 0; n < 4; ++n)
                acc[m][n] = (f32x4){0.f, 0.f, 0.f, 0.f};

        const unsigned short* lb = &lds[cur][0];
        #pragma unroll
        for (int kk = 0; kk < 4; ++kk) {
            bf16x8 bfr[4];
            #pragma unroll
            for (int n = 0; n < 4; ++n)
                bfr[n] = *(const bf16x8*)&lb[(wc*64 + n*16 + lrow) * LDS_ROW + kk*32 + kgrp*8];
            #pragma unroll
            for (int m = 0; m < 4; ++m)
                #pragma unroll
                for (int n = 0; n < 4; ++n)
                    acc[m][n] = __builtin_amdgcn_mfma_f32_16x16x32_bf16(
                                    af[m][kk], bfr[n], acc[m][n], 0, 0, 0);
        }

        // 3) cvt + write next B tile into the other buffer (vmcnt wait lands here)
        if (has_next) {
            unsigned short* dst = cur ? ldsw0 : ldsw1;
            #pragma unroll
            for (int it = 0; it < 16; ++it) {
                ushort4 p; p.x=f2bf(g[it].x); p.y=f2bf(g[it].y); p.z=f2bf(g[it].z); p.w=f2bf(g[it].w);
                *(ushort4*)(dst + it * 8 * LDS_ROW) = p;
            }
        }

        // 4) store C tile (no bounds checks: s % 128 == 0)
        float* op = orow + tc * BT;
        #pragma unroll
        for (int m = 0; m < 4; ++m)
            #pragma unroll
            for (int n = 0; n < 4; ++n)
                #pragma unroll
                for (int j = 0; j < 4; ++j)
                    op[(long long)(m * 16 + j) * s + n * 16] = acc[m][n][j];

        __syncthreads();
        cur ^= 1;
    }
}

extern "C" void kernel_launch(void* const* d_in, const int* in_sizes, int n_in,
                              void* d_out, int out_size, void* d_ws, size_t ws_size,
                              hipStream_t stream) {
    const float* A = (const float*)d_in[0];
    const float* B = (const float*)d_in[1];
    float* out = (float*)d_out;

    static const int S[NSEQ] = {1024, 768, 512, 1536, 256, 1280, 512, 1024};

    // offsets in ORIGINAL concat order
    int row_off[NSEQ]; long long out_off[NSEQ];
    int row = 0; long long o = 0;
    for (int i = 0; i < NSEQ; ++i) {
        row_off[i] = row; out_off[i] = o;
        row += S[i];
        o   += (long long)HEADS * S[i] * S[i];
    }

    // block order: descending t (long strips dispatch first -> no scheduling tail)
    static const int order[NSEQ] = {3, 5, 0, 7, 1, 2, 6, 4};

    SeqMap map;
    int blk = 0;
    for (int k = 0; k < NSEQ; ++k) {
        const int i = order[k];
        const int t = S[i] / BT;
        map.s[k]         = S[i];
        map.row_off[k]   = row_off[i];
        map.out_off[k]   = out_off[i];
        map.t[k]         = t;
        map.blk_start[k] = blk;
        blk += HEADS * t;
    }
    map.nblk = blk;   // 864, % 8 == 0

    qkt_strip_kernel<<<blk, 256, 0, stream>>>(A, B, out, map);
}